// Round 21
// baseline (165.444 us; speedup 1.0000x reference)
//
#include <hip/hip_runtime.h>
#include <hip/hip_bf16.h>

typedef __attribute__((ext_vector_type(8))) short bf16x8;
typedef __attribute__((ext_vector_type(4))) short s16x4;
typedef __attribute__((ext_vector_type(2))) int i32x2;
typedef __attribute__((ext_vector_type(4))) float f32x4;

__device__ __forceinline__ short f2bf(float f) {
  unsigned u = __builtin_bit_cast(unsigned, f);
  u = (u + 0x7FFFu + ((u >> 16) & 1u)) >> 16;
  return (short)u;
}

__device__ __forceinline__ void gload_lds16(const void* g, void* l) {
  __builtin_amdgcn_global_load_lds(
      (const __attribute__((address_space(1))) void*)g,
      (__attribute__((address_space(3))) void*)l, 16, 0, 0);
}

__device__ __forceinline__ f32x4 mfma16(s16x4 a, s16x4 b, f32x4 c) {
#if __has_builtin(__builtin_amdgcn_mfma_f32_16x16x16bf16_1k)
  return __builtin_amdgcn_mfma_f32_16x16x16bf16_1k(a, b, c, 0, 0, 0);
#else
  asm("v_mfma_f32_16x16x16_bf16 %0, %1, %2, %0" : "+v"(c) : "v"(a), "v"(b));
  return c;
#endif
}

#define SBAR()       asm volatile("s_barrier" ::: "memory")
#define WAIT_VM4()   asm volatile("s_waitcnt vmcnt(4)" ::: "memory")
#define WAIT_VM0()   asm volatile("s_waitcnt vmcnt(0)" ::: "memory")
#define WAIT_LGKM0() asm volatile("s_waitcnt lgkmcnt(0)" ::: "memory")

// ---------------------------------------------------------------- merged prep
// bid ranges: [0,15360) x->bf16 copy | [15360,18432) qkv_w^T |
// [18432,19456) proj_w^T | [19456,20416) expB fragment table.
__global__ void k_prep(const float* __restrict__ x, const float* __restrict__ qkv_w,
                       const float* __restrict__ proj_w, const float* __restrict__ table,
                       short* __restrict__ xb, short* __restrict__ qkv_wt,
                       short* __restrict__ proj_wt, float* __restrict__ expB) {
  const int bid = blockIdx.x;
  if (bid < 15360) {
    int i = bid * 256 + threadIdx.x;
    const float4 v = *(const float4*)(x + (size_t)i * 4);
    s16x4 o;
    o.x = f2bf(v.x); o.y = f2bf(v.y); o.z = f2bf(v.z); o.w = f2bf(v.w);
    *(s16x4*)(xb + (size_t)i * 4) = o;
  } else if (bid < 18432) {
    int i = (bid - 15360) * 256 + threadIdx.x;
    int k = i & 511, n = i >> 9;
    qkv_wt[i] = f2bf(qkv_w[(size_t)k * 1536 + n]);
  } else if (bid < 19456) {
    int i = (bid - 18432) * 256 + threadIdx.x;
    int k = i & 511, n = i >> 9;
    proj_wt[i] = f2bf(proj_w[(size_t)k * 512 + n]);
  } else {
    int i = (bid - 19456) * 256 + threadIdx.x;
    int lane = i & 63;
    int rest = i >> 6;
    int j = rest % 15;
    int hq = rest / 15;
    int q = (hq & 15) * 16 + (lane & 15);
    int h = hq >> 4;
    int kbase = j * 16 + ((lane >> 4) << 2);
    float4 o;
    float* op = &o.x;
#pragma unroll
    for (int r = 0; r < 4; ++r) {
      int k = kbase + r;
      int idx = ((q >> 4) - (k >> 4) + 15) * 31 + ((q & 15) - (k & 15) + 15);
      op[r] = __builtin_amdgcn_exp2f(table[idx * 16 + h] * 1.4426950408889634f);
    }
    *(float4*)(expB + (size_t)i * 4) = o;
  }
}

// ---------------------------------------------------------------- GEMM
// C = A(30720 x 512) * Bt(N x 512)^T + bias. BM=BN=256, 8 waves (2m x 4n of
// 128x64 wave tiles), BK=32, 2-deep counted-vmcnt pipeline (vmcnt(4), never
// drained in loop), frag-ordered LDS (0 conflicts), XCD-swizzled 1-D grid.
// M=30720 = 120 m-tiles (240 real tokens/batch; padding never computed).
// MODE 0: QKV epilogue. Q,V packed 8B to (b,h,d,t) stride-240; K scatter to
//         (b,h,t,d). Q pre-scaled by hd^-0.5*log2(e).
// MODE 1: proj epilogue (fp32, dense: fo[mm*512+c]).
// NOTE (session finding): this loop family is pinned at ~39 cyc/MFMA-slot per
// block regardless of barrier structure / phase count / wave count (R13-R19),
// matching the documented m97-structure per-step cost. Kept in its simplest
// green form.
template <int MODE, int NBN>
__global__ __launch_bounds__(512, 2)
void k_gemm(const short* __restrict__ A, const short* __restrict__ Bt,
            const float* __restrict__ bias,
            short* __restrict__ qo, short* __restrict__ ko, short* __restrict__ vo,
            float* __restrict__ fo) {
  __shared__ alignas(16) short lds[2][32][512];  // [buf][16 A-blk + 16 B-blk][frag]
  const int lane = threadIdx.x & 63;
  const int w = threadIdx.x >> 6;   // 0..7
  const int wm = w >> 2;            // 0..1 (m offset 128)
  const int wn = w & 3;             // 0..3 (n offset 64)
  const int arow = lane & 15;
  const int g = lane >> 4;
  const int kc8 = g * 8;

  const int nwg = 120 * NBN;
  const int bid = blockIdx.x;
  const int swz = (bid & 7) * (nwg >> 3) + (bid >> 3);
  const int nb = swz % NBN, mc = swz / NBN;
  const int n0 = nb * 256, m0 = mc * 256;

  const short* gsrc[4];
#pragma unroll
  for (int s = 0; s < 4; ++s) {
    const int t = w * 4 + s;
    gsrc[s] = (t < 16 ? A + (size_t)(m0 + t * 16 + arow) * 512
                      : Bt + (size_t)(n0 + (t - 16) * 16 + arow) * 512) + kc8;
  }

#define STAGE(buf, k0)                                       \
  {                                                          \
    _Pragma("unroll")                                        \
    for (int s = 0; s < 4; ++s)                              \
      gload_lds16(gsrc[s] + (k0), &lds[buf][w * 4 + s][0]);  \
  }

  float bv[4];
#pragma unroll
  for (int j = 0; j < 4; ++j) bv[j] = bias[n0 + wn * 64 + j * 16 + arow];

  f32x4 acc[8][4] = {};
  STAGE(0, 0);
  STAGE(1, 32);
#pragma unroll
  for (int kt = 0; kt < 16; ++kt) {
    const int cur = kt & 1;
    if (kt < 15) WAIT_VM4(); else WAIT_VM0();   // oldest stage (tile kt) landed
    SBAR();
    bf16x8 af[8], bfr[4];
#pragma unroll
    for (int i = 0; i < 8; ++i)
      af[i] = *(const bf16x8*)&lds[cur][wm * 8 + i][lane * 8];
#pragma unroll
    for (int j = 0; j < 4; ++j)
      bfr[j] = *(const bf16x8*)&lds[cur][16 + wn * 4 + j][lane * 8];
#pragma unroll
    for (int i = 0; i < 8; ++i)
#pragma unroll
      for (int j = 0; j < 4; ++j)
        acc[i][j] = __builtin_amdgcn_mfma_f32_16x16x32_bf16(af[i], bfr[j], acc[i][j], 0, 0, 0);
    WAIT_LGKM0();                               // all reads consumed
    __builtin_amdgcn_sched_barrier(0);
    SBAR();                                     // all waves' reads done -> reuse ok
    if (kt < 14) STAGE(cur, (kt + 2) * 32);     // prefetch 2 ahead
  }
#undef STAGE

  const float sc = 0.17677669529663687f * 1.4426950408889634f;
  if (MODE == 0) {
    const int part = n0 >> 9;                    // 0:Q 1:K 2:V (uniform per block)
    short* dst = part == 0 ? qo : (part == 1 ? ko : vo);
    const float osc = part == 0 ? sc : 1.f;
    if (part != 1) {
      // Q,V: (b,h,d,t) stride-240 -> lane's 4 consecutive t = one 8B store
#pragma unroll
      for (int i = 0; i < 8; ++i) {
        const int mm0 = m0 + wm * 128 + i * 16 + g * 4;
        const int bb = mm0 / 240, tt0 = mm0 - bb * 240;
#pragma unroll
        for (int j = 0; j < 4; ++j) {
          const int c = n0 + wn * 64 + j * 16 + arow;
          const int d = c & 31, hh = (c >> 5) & 15;
          s16x4 qv;
#pragma unroll
          for (int r = 0; r < 4; ++r)
            qv[r] = f2bf((acc[i][j][r] + bv[j]) * osc);
          *(s16x4*)(dst + ((size_t)(bb * 16 + hh) * 32 + d) * 240 + tt0) = qv;
        }
      }
    } else {
      // K: (b,h,t,d) scatter
#pragma unroll
      for (int i = 0; i < 8; ++i) {
        const int mm0 = m0 + wm * 128 + i * 16 + g * 4;
        const int bb = mm0 / 240, tt0 = mm0 - bb * 240;
#pragma unroll
        for (int j = 0; j < 4; ++j) {
          const int c = n0 + wn * 64 + j * 16 + arow;
          const int d = c & 31, hh = (c >> 5) & 15;
#pragma unroll
          for (int r = 0; r < 4; ++r)
            dst[((size_t)(bb * 16 + hh) * 240 + tt0 + r) * 32 + d] =
                f2bf(acc[i][j][r] + bv[j]);
        }
      }
    }
  } else {
    // proj: dense store, every row is a real token
#pragma unroll
    for (int i = 0; i < 8; ++i) {
      const int mm0 = m0 + wm * 128 + i * 16 + g * 4;
#pragma unroll
      for (int j = 0; j < 4; ++j) {
        const int c = n0 + wn * 64 + j * 16 + arow;
#pragma unroll
        for (int r = 0; r < 4; ++r)
          fo[(size_t)(mm0 + r) * 512 + c] = acc[i][j][r] + bv[j];
      }
    }
  }
}

// ---------------------------------------------------------------- attention
// One WG (8 waves, 512 thr) per (b,h). 15 q-tiles of 16 rows (240 real tokens;
// wave 7 runs only qt=0). Swapped QK^T: lane holds S[q=lane&15][k=j*16+4g+r]
// -> softmax row fully lane-local; P packs directly into the A-fragment of
// mfma_f32_16x16x16_bf16 for PV. Q,V arrive (b,h,d,t) stride-240; K (b,h,t,d).
// R21: h-major XCD decode — each XCD serves only 2 heads, so its expB slice
// (2 x 245KB = 490KB) stays L2-resident against ~460MB of block-level expB
// demand (vs 3.9MB working set = full L2 with bh-major dispatch). Pure
// bijective block permutation on a __syncthreads-only kernel (race-free).
__global__ __launch_bounds__(512, 4)
void k_attn(const short* __restrict__ Qg, const short* __restrict__ Kg,
            const short* __restrict__ Vg, const float* __restrict__ expB,
            short* __restrict__ O) {
  __shared__ alignas(16) short ldsK[15 * 512];      // frag-ordered K tiles
  __shared__ alignas(16) short ldsVT[32 * 264];     // V^T [d][t], stride 264
  const int lane = threadIdx.x & 63;
  const int w = threadIdx.x >> 6;                   // 0..7
  const int bid = blockIdx.x;
  const int swz = (bid & 7) * 256 + (bid >> 3);     // XCD-chunked (2048 = 8*256)
  const int h = swz >> 7;                           // 2 heads per XCD chunk
  const int b = swz & 127;
  const int bh = b * 16 + h;
  const short* Qb = Qg + (size_t)bh * 7680;         // 240*32
  const short* Kb = Kg + (size_t)bh * 7680;
  const short* Vb = Vg + (size_t)bh * 7680;
  const int arow = lane & 15;
  const int g = lane >> 4;

#pragma unroll
  for (int kt = 0; kt < 15; ++kt)
    if ((kt & 7) == w)
      gload_lds16(Kb + (kt * 16 + arow) * 32 + g * 8, &ldsK[kt * 512]);

  // V is (d,t) stride-240: build padded V^T in LDS (cols 240+ unused)
  for (int c2 = threadIdx.x; c2 < 960; c2 += 512) {   // 32 d x 30 chunks
    int d = c2 / 30, tc = c2 - d * 30;
    *(bf16x8*)&ldsVT[d * 264 + tc * 8] = *(const bf16x8*)(Vb + d * 240 + tc * 8);
  }

  // Q is (d,t) stride-240: per-element gather, once per block (q rows < 240)
  bf16x8 qf[2];
#pragma unroll
  for (int i = 0; i < 2; ++i) {
    if (w * 2 + i < 15) {
#pragma unroll
      for (int e = 0; e < 8; ++e)
        qf[i][e] = Qb[(g * 8 + e) * 240 + (w * 2 + i) * 16 + arow];
    }
  }
  __syncthreads();

  const f32x4 zf = {0.f, 0.f, 0.f, 0.f};
#pragma unroll
  for (int qt = 0; qt < 2; ++qt) {
    const int qtile = w * 2 + qt;
    if (qtile >= 15) continue;                      // wave-uniform skip (pad tile)
    f32x4 sacc[15];
#pragma unroll
    for (int j = 0; j < 15; ++j) {
      bf16x8 kf = *(const bf16x8*)&ldsK[j * 512 + lane * 8];
      sacc[j] = __builtin_amdgcn_mfma_f32_16x16x32_bf16(kf, qf[qt], zf, 0, 0, 0);
    }
    float m = fmaxf(fmaxf(sacc[0][0], sacc[0][1]), fmaxf(sacc[0][2], sacc[0][3]));
#pragma unroll
    for (int j = 1; j < 15; ++j)
      m = fmaxf(m, fmaxf(fmaxf(sacc[j][0], sacc[j][1]), fmaxf(sacc[j][2], sacc[j][3])));
    m = fmaxf(m, __shfl_xor(m, 16));
    m = fmaxf(m, __shfl_xor(m, 32));
    const float* ebp = expB + (size_t)((h * 16 + qtile) * 15) * 256 + lane * 4;
    float sum = 0.f;
    s16x4 pa[15];
#pragma unroll
    for (int j = 0; j < 15; ++j) {
      float4 eb = *(const float4*)(ebp + j * 256);
      float p0 = __builtin_amdgcn_exp2f(sacc[j][0] - m) * eb.x;
      float p1 = __builtin_amdgcn_exp2f(sacc[j][1] - m) * eb.y;
      float p2 = __builtin_amdgcn_exp2f(sacc[j][2] - m) * eb.z;
      float p3 = __builtin_amdgcn_exp2f(sacc[j][3] - m) * eb.w;
      sum += (p0 + p1) + (p2 + p3);
      i32x2 pk;
      asm("v_cvt_pk_bf16_f32 %0, %1, %2" : "=v"(pk.x) : "v"(p0), "v"(p1));
      asm("v_cvt_pk_bf16_f32 %0, %1, %2" : "=v"(pk.y) : "v"(p2), "v"(p3));
      pa[j] = __builtin_bit_cast(s16x4, pk);
    }
    sum += __shfl_xor(sum, 16);
    sum += __shfl_xor(sum, 32);
    float rs = __builtin_amdgcn_rcpf(sum);
    float rsr[4];
#pragma unroll
    for (int r = 0; r < 4; ++r)
      rsr[r] = __shfl(rs, (lane & 48) + ((lane & 48) >> 2) + r, 64);
    f32x4 oacc[2] = {};
#pragma unroll
    for (int j = 0; j < 15; ++j) {
#pragma unroll
      for (int dt = 0; dt < 2; ++dt) {
        s16x4 vt = *(const s16x4*)&ldsVT[(dt * 16 + arow) * 264 + j * 16 + g * 4];
        oacc[dt] = mfma16(pa[j], vt, oacc[dt]);
      }
    }
    const int q0 = qtile * 16;
#pragma unroll
    for (int dt = 0; dt < 2; ++dt)
#pragma unroll
      for (int r = 0; r < 4; ++r)
        O[(size_t)(b * 240 + q0 + 4 * g + r) * 512 + h * 32 + dt * 16 + arow] =
            f2bf(oacc[dt][r] * rsr[r]);
  }
}

// ---------------------------------------------------------------- launch

extern "C" void kernel_launch(void* const* d_in, const int* in_sizes, int n_in,
                              void* d_out, int out_size, void* d_ws, size_t ws_size,
                              hipStream_t stream) {
  const float* x      = (const float*)d_in[0];
  const float* qkv_w  = (const float*)d_in[1];
  const float* qkv_b  = (const float*)d_in[2];
  const float* proj_w = (const float*)d_in[3];
  const float* proj_b = (const float*)d_in[4];
  const float* table  = (const float*)d_in[5];
  float* out = (float*)d_out;

  char* ws = (char*)d_ws;
  short* xb      = (short*)(ws);                 // 31,457,280 B (reused as attn_out)
  short* Qg      = (short*)(ws + 33554432u);     // 31,457,280 B  (b,h,d,t) stride-240
  short* Kg      = (short*)(ws + 67108864u);     // 31,457,280 B  (b,h,t,d)
  short* Vg      = (short*)(ws + 100663296u);    // 31,457,280 B  (b,h,d,t) stride-240
  float* expBf   = (float*)(ws + 134217728u);    //  3,932,160 B
  short* qkv_wt  = (short*)(ws + 138412032u);    //  1,572,864 B
  short* proj_wt = (short*)(ws + 139984896u);    //    524,288 B

  k_prep<<<20416, 256, 0, stream>>>(x, qkv_w, proj_w, table, xb, qkv_wt, proj_wt, expBf);
  k_gemm<0, 6><<<720, 512, 0, stream>>>(xb, qkv_wt, qkv_b, Qg, Kg, Vg, nullptr);
  k_attn<<<2048, 512, 0, stream>>>(Qg, Kg, Vg, expBf, xb);
  k_gemm<1, 2><<<240, 512, 0, stream>>>(xb, proj_wt, proj_b, nullptr, nullptr, nullptr, out);
}

// Round 22
// 157.240 us; speedup vs baseline: 1.0522x; 1.0522x over previous
//
#include <hip/hip_runtime.h>
#include <hip/hip_bf16.h>

typedef __attribute__((ext_vector_type(8))) short bf16x8;
typedef __attribute__((ext_vector_type(4))) short s16x4;
typedef __attribute__((ext_vector_type(2))) int i32x2;
typedef __attribute__((ext_vector_type(4))) float f32x4;

__device__ __forceinline__ short f2bf(float f) {
  unsigned u = __builtin_bit_cast(unsigned, f);
  u = (u + 0x7FFFu + ((u >> 16) & 1u)) >> 16;
  return (short)u;
}

__device__ __forceinline__ void gload_lds16(const void* g, void* l) {
  __builtin_amdgcn_global_load_lds(
      (const __attribute__((address_space(1))) void*)g,
      (__attribute__((address_space(3))) void*)l, 16, 0, 0);
}

__device__ __forceinline__ f32x4 mfma16(s16x4 a, s16x4 b, f32x4 c) {
#if __has_builtin(__builtin_amdgcn_mfma_f32_16x16x16bf16_1k)
  return __builtin_amdgcn_mfma_f32_16x16x16bf16_1k(a, b, c, 0, 0, 0);
#else
  asm("v_mfma_f32_16x16x16_bf16 %0, %1, %2, %0" : "+v"(c) : "v"(a), "v"(b));
  return c;
#endif
}

#define SBAR()       asm volatile("s_barrier" ::: "memory")
#define WAIT_VM4()   asm volatile("s_waitcnt vmcnt(4)" ::: "memory")
#define WAIT_VM0()   asm volatile("s_waitcnt vmcnt(0)" ::: "memory")
#define WAIT_LGKM0() asm volatile("s_waitcnt lgkmcnt(0)" ::: "memory")

// ---------------------------------------------------------------- merged prep
// bid ranges: [0,15360) x->bf16 copy | [15360,18432) qkv_w^T |
// [18432,19456) proj_w^T | [19456,20416) expB fragment table.
__global__ void k_prep(const float* __restrict__ x, const float* __restrict__ qkv_w,
                       const float* __restrict__ proj_w, const float* __restrict__ table,
                       short* __restrict__ xb, short* __restrict__ qkv_wt,
                       short* __restrict__ proj_wt, float* __restrict__ expB) {
  const int bid = blockIdx.x;
  if (bid < 15360) {
    int i = bid * 256 + threadIdx.x;
    const float4 v = *(const float4*)(x + (size_t)i * 4);
    s16x4 o;
    o.x = f2bf(v.x); o.y = f2bf(v.y); o.z = f2bf(v.z); o.w = f2bf(v.w);
    *(s16x4*)(xb + (size_t)i * 4) = o;
  } else if (bid < 18432) {
    int i = (bid - 15360) * 256 + threadIdx.x;
    int k = i & 511, n = i >> 9;
    qkv_wt[i] = f2bf(qkv_w[(size_t)k * 1536 + n]);
  } else if (bid < 19456) {
    int i = (bid - 18432) * 256 + threadIdx.x;
    int k = i & 511, n = i >> 9;
    proj_wt[i] = f2bf(proj_w[(size_t)k * 512 + n]);
  } else {
    int i = (bid - 19456) * 256 + threadIdx.x;
    int lane = i & 63;
    int rest = i >> 6;
    int j = rest % 15;
    int hq = rest / 15;
    int q = (hq & 15) * 16 + (lane & 15);
    int h = hq >> 4;
    int kbase = j * 16 + ((lane >> 4) << 2);
    float4 o;
    float* op = &o.x;
#pragma unroll
    for (int r = 0; r < 4; ++r) {
      int k = kbase + r;
      int idx = ((q >> 4) - (k >> 4) + 15) * 31 + ((q & 15) - (k & 15) + 15);
      op[r] = __builtin_amdgcn_exp2f(table[idx * 16 + h] * 1.4426950408889634f);
    }
    *(float4*)(expB + (size_t)i * 4) = o;
  }
}

// ---------------------------------------------------------------- GEMM
// C = A(30720 x 512) * Bt(N x 512)^T + bias. BM=BN=256, 8 waves (2m x 4n of
// 128x64 wave tiles), BK=32, 2-deep counted-vmcnt pipeline (vmcnt(4), never
// drained in loop), frag-ordered LDS (0 conflicts), XCD-swizzled 1-D grid.
// M=30720 = 120 m-tiles (240 real tokens/batch; padding never computed).
// MODE 0: QKV epilogue. Q,V packed 8B to (b,h,d,t) stride-240; K scatter to
//         (b,h,t,d). Q pre-scaled by hd^-0.5*log2(e).
// MODE 1: proj epilogue (fp32, dense: fo[mm*512+c]).
// NOTE (session finding): this loop family is pinned at ~39 cyc/MFMA-slot per
// block regardless of barrier structure / phase count / wave count (R13-R19),
// matching the documented m97-structure per-step cost. Kept in its simplest
// green form.
template <int MODE, int NBN>
__global__ __launch_bounds__(512, 2)
void k_gemm(const short* __restrict__ A, const short* __restrict__ Bt,
            const float* __restrict__ bias,
            short* __restrict__ qo, short* __restrict__ ko, short* __restrict__ vo,
            float* __restrict__ fo) {
  __shared__ alignas(16) short lds[2][32][512];  // [buf][16 A-blk + 16 B-blk][frag]
  const int lane = threadIdx.x & 63;
  const int w = threadIdx.x >> 6;   // 0..7
  const int wm = w >> 2;            // 0..1 (m offset 128)
  const int wn = w & 3;             // 0..3 (n offset 64)
  const int arow = lane & 15;
  const int g = lane >> 4;
  const int kc8 = g * 8;

  const int nwg = 120 * NBN;
  const int bid = blockIdx.x;
  const int swz = (bid & 7) * (nwg >> 3) + (bid >> 3);
  const int nb = swz % NBN, mc = swz / NBN;
  const int n0 = nb * 256, m0 = mc * 256;

  const short* gsrc[4];
#pragma unroll
  for (int s = 0; s < 4; ++s) {
    const int t = w * 4 + s;
    gsrc[s] = (t < 16 ? A + (size_t)(m0 + t * 16 + arow) * 512
                      : Bt + (size_t)(n0 + (t - 16) * 16 + arow) * 512) + kc8;
  }

#define STAGE(buf, k0)                                       \
  {                                                          \
    _Pragma("unroll")                                        \
    for (int s = 0; s < 4; ++s)                              \
      gload_lds16(gsrc[s] + (k0), &lds[buf][w * 4 + s][0]);  \
  }

  float bv[4];
#pragma unroll
  for (int j = 0; j < 4; ++j) bv[j] = bias[n0 + wn * 64 + j * 16 + arow];

  f32x4 acc[8][4] = {};
  STAGE(0, 0);
  STAGE(1, 32);
#pragma unroll
  for (int kt = 0; kt < 16; ++kt) {
    const int cur = kt & 1;
    if (kt < 15) WAIT_VM4(); else WAIT_VM0();   // oldest stage (tile kt) landed
    SBAR();
    bf16x8 af[8], bfr[4];
#pragma unroll
    for (int i = 0; i < 8; ++i)
      af[i] = *(const bf16x8*)&lds[cur][wm * 8 + i][lane * 8];
#pragma unroll
    for (int j = 0; j < 4; ++j)
      bfr[j] = *(const bf16x8*)&lds[cur][16 + wn * 4 + j][lane * 8];
#pragma unroll
    for (int i = 0; i < 8; ++i)
#pragma unroll
      for (int j = 0; j < 4; ++j)
        acc[i][j] = __builtin_amdgcn_mfma_f32_16x16x32_bf16(af[i], bfr[j], acc[i][j], 0, 0, 0);
    WAIT_LGKM0();                               // all reads consumed
    __builtin_amdgcn_sched_barrier(0);
    SBAR();                                     // all waves' reads done -> reuse ok
    if (kt < 14) STAGE(cur, (kt + 2) * 32);     // prefetch 2 ahead
  }
#undef STAGE

  const float sc = 0.17677669529663687f * 1.4426950408889634f;
  if (MODE == 0) {
    const int part = n0 >> 9;                    // 0:Q 1:K 2:V (uniform per block)
    short* dst = part == 0 ? qo : (part == 1 ? ko : vo);
    const float osc = part == 0 ? sc : 1.f;
    if (part != 1) {
      // Q,V: (b,h,d,t) stride-240 -> lane's 4 consecutive t = one 8B store
#pragma unroll
      for (int i = 0; i < 8; ++i) {
        const int mm0 = m0 + wm * 128 + i * 16 + g * 4;
        const int bb = mm0 / 240, tt0 = mm0 - bb * 240;
#pragma unroll
        for (int j = 0; j < 4; ++j) {
          const int c = n0 + wn * 64 + j * 16 + arow;
          const int d = c & 31, hh = (c >> 5) & 15;
          s16x4 qv;
#pragma unroll
          for (int r = 0; r < 4; ++r)
            qv[r] = f2bf((acc[i][j][r] + bv[j]) * osc);
          *(s16x4*)(dst + ((size_t)(bb * 16 + hh) * 32 + d) * 240 + tt0) = qv;
        }
      }
    } else {
      // K: (b,h,t,d) scatter
#pragma unroll
      for (int i = 0; i < 8; ++i) {
        const int mm0 = m0 + wm * 128 + i * 16 + g * 4;
        const int bb = mm0 / 240, tt0 = mm0 - bb * 240;
#pragma unroll
        for (int j = 0; j < 4; ++j) {
          const int c = n0 + wn * 64 + j * 16 + arow;
          const int d = c & 31, hh = (c >> 5) & 15;
#pragma unroll
          for (int r = 0; r < 4; ++r)
            dst[((size_t)(bb * 16 + hh) * 240 + tt0 + r) * 32 + d] =
                f2bf(acc[i][j][r] + bv[j]);
        }
      }
    }
  } else {
    // proj: dense store, every row is a real token
#pragma unroll
    for (int i = 0; i < 8; ++i) {
      const int mm0 = m0 + wm * 128 + i * 16 + g * 4;
#pragma unroll
      for (int j = 0; j < 4; ++j) {
        const int c = n0 + wn * 64 + j * 16 + arow;
#pragma unroll
        for (int r = 0; r < 4; ++r)
          fo[(size_t)(mm0 + r) * 512 + c] = acc[i][j][r] + bv[j];
      }
    }
  }
}

// ---------------------------------------------------------------- attention
// One WG (8 waves, 512 thr) per (b,h). 15 q-tiles of 16 rows (240 real tokens;
// wave 7 runs only qt=0). Swapped QK^T: lane holds S[q=lane&15][k=j*16+4g+r]
// -> softmax row fully lane-local; P packs directly into the A-fragment of
// mfma_f32_16x16x16_bf16 for PV. Q,V arrive (b,h,d,t) stride-240; K (b,h,t,d).
// (bh-major dispatch: R21's h-major XCD decode measured -8us -> reverted.)
__global__ __launch_bounds__(512, 4)
void k_attn(const short* __restrict__ Qg, const short* __restrict__ Kg,
            const short* __restrict__ Vg, const float* __restrict__ expB,
            short* __restrict__ O) {
  __shared__ alignas(16) short ldsK[15 * 512];      // frag-ordered K tiles
  __shared__ alignas(16) short ldsVT[32 * 264];     // V^T [d][t], stride 264
  const int lane = threadIdx.x & 63;
  const int w = threadIdx.x >> 6;                   // 0..7
  const int bh = blockIdx.x;
  const int h = bh & 15, b = bh >> 4;
  const short* Qb = Qg + (size_t)bh * 7680;         // 240*32
  const short* Kb = Kg + (size_t)bh * 7680;
  const short* Vb = Vg + (size_t)bh * 7680;
  const int arow = lane & 15;
  const int g = lane >> 4;

#pragma unroll
  for (int kt = 0; kt < 15; ++kt)
    if ((kt & 7) == w)
      gload_lds16(Kb + (kt * 16 + arow) * 32 + g * 8, &ldsK[kt * 512]);

  // V is (d,t) stride-240: build padded V^T in LDS (cols 240+ unused)
  for (int c2 = threadIdx.x; c2 < 960; c2 += 512) {   // 32 d x 30 chunks
    int d = c2 / 30, tc = c2 - d * 30;
    *(bf16x8*)&ldsVT[d * 264 + tc * 8] = *(const bf16x8*)(Vb + d * 240 + tc * 8);
  }

  // Q is (d,t) stride-240: per-element gather, once per block (q rows < 240)
  bf16x8 qf[2];
#pragma unroll
  for (int i = 0; i < 2; ++i) {
    if (w * 2 + i < 15) {
#pragma unroll
      for (int e = 0; e < 8; ++e)
        qf[i][e] = Qb[(g * 8 + e) * 240 + (w * 2 + i) * 16 + arow];
    }
  }
  __syncthreads();

  const f32x4 zf = {0.f, 0.f, 0.f, 0.f};
#pragma unroll
  for (int qt = 0; qt < 2; ++qt) {
    const int qtile = w * 2 + qt;
    if (qtile >= 15) continue;                      // wave-uniform skip (pad tile)
    f32x4 sacc[15];
#pragma unroll
    for (int j = 0; j < 15; ++j) {
      bf16x8 kf = *(const bf16x8*)&ldsK[j * 512 + lane * 8];
      sacc[j] = __builtin_amdgcn_mfma_f32_16x16x32_bf16(kf, qf[qt], zf, 0, 0, 0);
    }
    float m = fmaxf(fmaxf(sacc[0][0], sacc[0][1]), fmaxf(sacc[0][2], sacc[0][3]));
#pragma unroll
    for (int j = 1; j < 15; ++j)
      m = fmaxf(m, fmaxf(fmaxf(sacc[j][0], sacc[j][1]), fmaxf(sacc[j][2], sacc[j][3])));
    m = fmaxf(m, __shfl_xor(m, 16));
    m = fmaxf(m, __shfl_xor(m, 32));
    const float* ebp = expB + (size_t)((h * 16 + qtile) * 15) * 256 + lane * 4;
    float sum = 0.f;
    s16x4 pa[15];
#pragma unroll
    for (int j = 0; j < 15; ++j) {
      float4 eb = *(const float4*)(ebp + j * 256);
      float p0 = __builtin_amdgcn_exp2f(sacc[j][0] - m) * eb.x;
      float p1 = __builtin_amdgcn_exp2f(sacc[j][1] - m) * eb.y;
      float p2 = __builtin_amdgcn_exp2f(sacc[j][2] - m) * eb.z;
      float p3 = __builtin_amdgcn_exp2f(sacc[j][3] - m) * eb.w;
      sum += (p0 + p1) + (p2 + p3);
      i32x2 pk;
      asm("v_cvt_pk_bf16_f32 %0, %1, %2" : "=v"(pk.x) : "v"(p0), "v"(p1));
      asm("v_cvt_pk_bf16_f32 %0, %1, %2" : "=v"(pk.y) : "v"(p2), "v"(p3));
      pa[j] = __builtin_bit_cast(s16x4, pk);
    }
    sum += __shfl_xor(sum, 16);
    sum += __shfl_xor(sum, 32);
    float rs = __builtin_amdgcn_rcpf(sum);
    float rsr[4];
#pragma unroll
    for (int r = 0; r < 4; ++r)
      rsr[r] = __shfl(rs, (lane & 48) + ((lane & 48) >> 2) + r, 64);
    f32x4 oacc[2] = {};
#pragma unroll
    for (int j = 0; j < 15; ++j) {
#pragma unroll
      for (int dt = 0; dt < 2; ++dt) {
        s16x4 vt = *(const s16x4*)&ldsVT[(dt * 16 + arow) * 264 + j * 16 + g * 4];
        oacc[dt] = mfma16(pa[j], vt, oacc[dt]);
      }
    }
    const int q0 = qtile * 16;
#pragma unroll
    for (int dt = 0; dt < 2; ++dt)
#pragma unroll
      for (int r = 0; r < 4; ++r)
        O[(size_t)(b * 240 + q0 + 4 * g + r) * 512 + h * 32 + dt * 16 + arow] =
            f2bf(oacc[dt][r] * rsr[r]);
  }
}

// ---------------------------------------------------------------- launch

extern "C" void kernel_launch(void* const* d_in, const int* in_sizes, int n_in,
                              void* d_out, int out_size, void* d_ws, size_t ws_size,
                              hipStream_t stream) {
  const float* x      = (const float*)d_in[0];
  const float* qkv_w  = (const float*)d_in[1];
  const float* qkv_b  = (const float*)d_in[2];
  const float* proj_w = (const float*)d_in[3];
  const float* proj_b = (const float*)d_in[4];
  const float* table  = (const float*)d_in[5];
  float* out = (float*)d_out;

  char* ws = (char*)d_ws;
  short* xb      = (short*)(ws);                 // 31,457,280 B (reused as attn_out)
  short* Qg      = (short*)(ws + 33554432u);     // 31,457,280 B  (b,h,d,t) stride-240
  short* Kg      = (short*)(ws + 67108864u);     // 31,457,280 B  (b,h,t,d)
  short* Vg      = (short*)(ws + 100663296u);    // 31,457,280 B  (b,h,d,t) stride-240
  float* expBf   = (float*)(ws + 134217728u);    //  3,932,160 B
  short* qkv_wt  = (short*)(ws + 138412032u);    //  1,572,864 B
  short* proj_wt = (short*)(ws + 139984896u);    //    524,288 B

  k_prep<<<20416, 256, 0, stream>>>(x, qkv_w, proj_w, table, xb, qkv_wt, proj_wt, expBf);
  k_gemm<0, 6><<<720, 512, 0, stream>>>(xb, qkv_wt, qkv_b, Qg, Kg, Vg, nullptr);
  k_attn<<<2048, 512, 0, stream>>>(Qg, Kg, Vg, expBf, xb);
  k_gemm<1, 2><<<240, 512, 0, stream>>>(xb, proj_wt, proj_b, nullptr, nullptr, nullptr, out);
}